// Round 5
// baseline (592.275 us; speedup 1.0000x reference)
//
#include <hip/hip_runtime.h>
#include <hip/hip_bf16.h>
#include <cstdint>
#include <cstddef>

// Problem constants
#define BS   16
#define CIN  256
#define COUT 256
#define HID  16
#define KNUM 5
#define TEMP 30.0f
#define NPIX 6400   // 80*80

typedef _Float16 half8 __attribute__((ext_vector_type(8)));
typedef float    f32x4 __attribute__((ext_vector_type(4)));

// ---------------------------------------------------------------------------
// Kernel 1: global average pool (f32 x, exact).  x[b][c][6400] -> pooled[b*256+c]
// ---------------------------------------------------------------------------
__global__ void pool_kernel(const float* __restrict__ x, float* __restrict__ pooled) {
    const int bc = blockIdx.x;
    const float* p = x + (size_t)bc * NPIX;
    float s = 0.f;
    for (int i = threadIdx.x; i < NPIX; i += 256) s += p[i];
    #pragma unroll
    for (int off = 32; off; off >>= 1) s += __shfl_down(s, off, 64);
    __shared__ float red[4];
    if ((threadIdx.x & 63) == 0) red[threadIdx.x >> 6] = s;
    __syncthreads();
    if (threadIdx.x == 0)
        pooled[bc] = (red[0] + red[1] + red[2] + red[3]) * (1.f / (float)NPIX);
}

// ---------------------------------------------------------------------------
// Kernel 2: x transpose f32 -> f16, [b][c][px] -> xt[b][px][c].
// 16 B stores (half8): thread handles (px = t&63, c-chunks of 8).
// Loads lane-coalesced (64 consecutive px per wave); stores 16 B granules
// that fill each 128 B line across the thread's 8 k-iterations.
// ---------------------------------------------------------------------------
__global__ __launch_bounds__(256)
void xpose_kernel(const float* __restrict__ x, _Float16* __restrict__ xt) {
    const int b = blockIdx.y, p0 = blockIdx.x * 64;
    const int pl = threadIdx.x & 63, cq = threadIdx.x >> 6;
    const int px = p0 + pl;
    const float* xb = x + (size_t)b * CIN * NPIX + px;
    _Float16* tp = xt + ((size_t)b * NPIX + px) * CIN;
    #pragma unroll
    for (int k = 0; k < 8; ++k) {
        const int c0 = cq * 64 + k * 8;
        float v[8];
        #pragma unroll
        for (int j = 0; j < 8; ++j) v[j] = xb[(size_t)(c0 + j) * NPIX];
        half8 h;
        #pragma unroll
        for (int j = 0; j < 8; ++j) h[j] = (_Float16)v[j];
        *(half8*)(tp + c0) = h;
    }
}

// ---------------------------------------------------------------------------
// Kernel 3: attention head (per sample). pooled holds MEAN.
//   coef[b][d][s] = k2_att[d] * sum_k n_att[k]*[P_k[d]==s]
// ---------------------------------------------------------------------------
__global__ void attn_kernel(const float* __restrict__ pooled,
                            const float* __restrict__ b_base,
                            const float* __restrict__ b_extra,
                            const float* __restrict__ w_net,
                            const float* __restrict__ w_nfc,
                            const float* __restrict__ w_cin,
                            const float* __restrict__ w_k2,
                            const float* __restrict__ w_out,
                            float* __restrict__ cin_att,
                            float* __restrict__ out_att,
                            float* __restrict__ agg_b,
                            float* __restrict__ coef) {
    const int b = blockIdx.x;
    const int t = threadIdx.x;
    __shared__ float sp[CIN];
    __shared__ float sh[HID];
    __shared__ float sn[KNUM];
    __shared__ float sk2[9];

    sp[t] = pooled[b * CIN + t];
    __syncthreads();

    if (t < HID) {
        float a = 0.f;
        for (int c = 0; c < CIN; ++c) a += sp[c] * w_net[t * CIN + c];
        sh[t] = fmaxf(a, 0.f);
    }
    __syncthreads();

    if (t == 0) {
        float l[KNUM], m = -1e30f;
        for (int k = 0; k < KNUM; ++k) {
            float a = 0.f;
            for (int j = 0; j < HID; ++j) a += sh[j] * w_nfc[k * HID + j];
            l[k] = a / TEMP;
            m = fmaxf(m, l[k]);
        }
        float ssum = 0.f;
        for (int k = 0; k < KNUM; ++k) { l[k] = __expf(l[k] - m); ssum += l[k]; }
        for (int k = 0; k < KNUM; ++k) sn[k] = l[k] / ssum;
    }
    if (t < 9) {
        float a = 0.f;
        for (int j = 0; j < HID; ++j) a += sh[j] * w_k2[t * HID + j];
        sk2[t] = 1.f / (1.f + __expf(-a));
    }
    __syncthreads();

    {
        float a = 0.f, o = 0.f;
        for (int j = 0; j < HID; ++j) {
            a += sh[j] * w_cin[t * HID + j];
            o += sh[j] * w_out[t * HID + j];
        }
        cin_att[b * CIN + t] = 1.f / (1.f + __expf(-a));
        out_att[b * COUT + t] = 1.f / (1.f + __expf(-o));
        float bb = sn[0] * b_base[t];
        for (int k = 1; k < KNUM; ++k) bb += sn[k] * b_extra[(k - 1) * COUT + t];
        agg_b[b * COUT + t] = bb;
    }

    if (t < 81) {
        const int P45[9]  = {3, 0, 1, 6, 4, 2, 7, 8, 5};
        const int P90[9]  = {6, 3, 0, 7, 4, 1, 8, 5, 2};
        const int P135[9] = {7, 6, 3, 8, 4, 0, 5, 2, 1};
        const int P180[9] = {8, 7, 6, 5, 4, 3, 2, 1, 0};
        const int d = t / 9, s = t % 9;
        float c = 0.f;
        if (d == s)        c += sn[0];
        if (P45[d]  == s)  c += sn[1];
        if (P90[d]  == s)  c += sn[2];
        if (P135[d] == s)  c += sn[3];
        if (P180[d] == s)  c += sn[4];
        coef[b * 81 + t] = c * sk2[d];
    }
}

// ---------------------------------------------------------------------------
// Kernel 4: weight synthesis, f16, MFMA A-fragment order:
//   wsyn[b][icb(8)][tap(9)][kb(4)][o(256)][j(8)]
//   value = out_att[b][o]*cin_att[b][i]*sum_s coef[b][tap][s]*w_base[o][i][s]
//   with i = icb*32 + kb*8 + j.
// ---------------------------------------------------------------------------
__global__ __launch_bounds__(256)
void wsyn_f16_kernel(const float* __restrict__ w_base,
                     const float* __restrict__ cin_att,
                     const float* __restrict__ out_att,
                     const float* __restrict__ coef,
                     _Float16* __restrict__ wsyn) {
    const int icb = blockIdx.x, og = blockIdx.y, b = blockIdx.z;
    const int t = threadIdx.x;
    const int kb = t >> 6, o_l = t & 63;
    const int o = og * 64 + o_l;
    const int i0 = icb * 32 + kb * 8;

    __shared__ float sc[81];
    if (t < 81) sc[t] = coef[b * 81 + t];
    __syncthreads();

    const float so = out_att[b * COUT + o];
    float wb[8][9], sci[8];
    const float* wp = w_base + ((size_t)o * CIN + i0) * 9;
    #pragma unroll
    for (int j = 0; j < 8; ++j) {
        sci[j] = cin_att[b * CIN + i0 + j] * so;
        #pragma unroll
        for (int s = 0; s < 9; ++s) wb[j][s] = wp[j * 9 + s];
    }
    #pragma unroll
    for (int tap = 0; tap < 9; ++tap) {
        half8 h;
        #pragma unroll
        for (int j = 0; j < 8; ++j) {
            float a = 0.f;
            #pragma unroll
            for (int s = 0; s < 9; ++s) a = fmaf(sc[tap * 9 + s], wb[j][s], a);
            h[j] = (_Float16)(a * sci[j]);
        }
        *(half8*)(wsyn + ((size_t)(b * 8 + icb) * 36 + tap * 4 + kb) * 2048
                        + (size_t)o * 8) = h;
    }
}

// ---------------------------------------------------------------------------
// Kernel 5: MFMA implicit-GEMM conv, v2.
// Block: 64 o x 256 px (16x16 spatial), one sample; 4 waves (wave = 4 px rows).
// W (A-frags) in REGISTERS via per-tap pipelined global loads (L2-resident).
// x halo single-buffered in LDS (25.9 KB) with T14 split: issue x[icb+1]
// global loads before compute, ds_write after the post-compute barrier.
// __launch_bounds__(256,3): 3 blocks/CU (12 waves), VGPR cap 170.
// ---------------------------------------------------------------------------
__global__ __launch_bounds__(256, 3)
void conv_mfma_kernel(const _Float16* __restrict__ xt,
                      const _Float16* __restrict__ wsyn,
                      const float* __restrict__ agg_b,
                      float* __restrict__ y) {
    const int tile = blockIdx.x;          // 0..24
    const int tc = tile % 5, tr = tile / 5;
    const int og = blockIdx.y;
    const int b = blockIdx.z;

    __shared__ _Float16 xlds[12960];      // 324 px x 40 halves (80 B) = 25.9 KB

    const int t = threadIdx.x;
    const int lane = t & 63, l15 = lane & 15, l4 = lane >> 4, w = t >> 6;
    const int row0 = tr * 16 - 1, col0 = tc * 16 - 1;

    // ---- hoisted x-staging geometry (per-thread, icb-invariant) ------------
    // px_base[it] = (gr*80+gc)*256 + part*8 (halves), or -1 if out of bounds.
    int px_base[6], lds_byte[6];
    #pragma unroll
    for (int it = 0; it < 6; ++it) {
        const int idx = t + it * 256;
        px_base[it] = -1; lds_byte[it] = 0;
        if (idx < 1296) {
            const int rc = idx >> 2, part = idx & 3;
            const int rr = rc / 18, cc = rc % 18;
            const int gr = row0 + rr, gc = col0 + cc;
            lds_byte[it] = rc * 80 + part * 16;
            if ((unsigned)gr < 80u && (unsigned)gc < 80u)
                px_base[it] = (gr * 80 + gc) * CIN + part * 8;
        }
    }

    f32x4 acc[4][4];
    const f32x4 z = {0.f, 0.f, 0.f, 0.f};
    #pragma unroll
    for (int a = 0; a < 4; ++a)
        #pragma unroll
        for (int p = 0; p < 4; ++p) acc[a][p] = z;

    const _Float16* gx  = xt + (size_t)b * NPIX * CIN;
    const _Float16* gw0 = wsyn + (size_t)b * 8 * 73728 + og * 512
                        + (size_t)l4 * 2048 + (size_t)l15 * 8;

    // ---- prologue: stage x[0] ---------------------------------------------
    {
        uint4 xr[6];
        #pragma unroll
        for (int it = 0; it < 6; ++it) {
            xr[it] = make_uint4(0u, 0u, 0u, 0u);
            if (px_base[it] >= 0)
                xr[it] = *(const uint4*)(gx + px_base[it]);
        }
        #pragma unroll
        for (int it = 0; it < 6; ++it)
            if (t + it * 256 < 1296)
                *(uint4*)((char*)xlds + lds_byte[it]) = xr[it];
    }
    __syncthreads();

    for (int icb = 0; icb < 8; ++icb) {
        // ---- T14: issue x[icb+1] global loads early (regs) ----------------
        uint4 xn[6];
        #pragma unroll
        for (int it = 0; it < 6; ++it) xn[it] = make_uint4(0u, 0u, 0u, 0u);
        if (icb < 7) {
            #pragma unroll
            for (int it = 0; it < 6; ++it)
                if (px_base[it] >= 0)
                    xn[it] = *(const uint4*)(gx + px_base[it] + (icb + 1) * 32);
        }

        // ---- compute: A-frags from global, pipelined one tap ahead --------
        const _Float16* gw = gw0 + (size_t)icb * 73728;
        half8 An[4];
        #pragma unroll
        for (int ot = 0; ot < 4; ++ot)
            An[ot] = *(const half8*)(gw + (size_t)ot * 128);  // tap 0
        #pragma unroll
        for (int tap = 0; tap < 9; ++tap) {
            const int dh = tap / 3, dw = tap % 3;
            half8 A[4];
            #pragma unroll
            for (int ot = 0; ot < 4; ++ot) A[ot] = An[ot];
            if (tap < 8) {
                #pragma unroll
                for (int ot = 0; ot < 4; ++ot)
                    An[ot] = *(const half8*)(gw + (size_t)(tap + 1) * 8192
                                                + (size_t)ot * 128);
            }
            half8 Bv[4];
            #pragma unroll
            for (int pt = 0; pt < 4; ++pt)
                Bv[pt] = *(const half8*)((const char*)xlds +
                        ((w * 4 + pt + dh) * 18 + l15 + dw) * 80 + l4 * 16);
            #pragma unroll
            for (int ot = 0; ot < 4; ++ot)
                #pragma unroll
                for (int pt = 0; pt < 4; ++pt)
                    acc[ot][pt] = __builtin_amdgcn_mfma_f32_16x16x32_f16(
                        A[ot], Bv[pt], acc[ot][pt], 0, 0, 0);
        }
        __syncthreads();              // all waves done reading xlds
        if (icb < 7) {
            #pragma unroll
            for (int it = 0; it < 6; ++it)
                if (t + it * 256 < 1296)
                    *(uint4*)((char*)xlds + lds_byte[it]) = xn[it];
        }
        __syncthreads();              // staged data visible
    }

    // ---- epilogue: bias + store -------------------------------------------
    const int prow0 = tr * 16 + w * 4;
    #pragma unroll
    for (int ot = 0; ot < 4; ++ot) {
        const int o = og * 64 + ot * 16 + l4 * 4;
        #pragma unroll
        for (int q = 0; q < 4; ++q) {
            const float bv = agg_b[b * COUT + o + q];
            #pragma unroll
            for (int pt = 0; pt < 4; ++pt)
                y[(size_t)(b * COUT + o + q) * NPIX + (prow0 + pt) * 80
                  + tc * 16 + l15] = acc[ot][pt][q] + bv;
        }
    }
}

// ===========================================================================
// Fallback fp32 path (proven correct at 1683 us) — used only if ws too small.
// ===========================================================================
__global__ void wsyn_kernel(const float* __restrict__ w_base,
                            const float* __restrict__ cin_att,
                            const float* __restrict__ out_att,
                            const float* __restrict__ coef,
                            float* __restrict__ wsyn) {
    const int i = blockIdx.x;
    const int o = threadIdx.x;
    __shared__ float sc[BS][81];
    __shared__ float sci[BS];
    for (int l = o; l < BS * 81; l += 256) sc[l / 81][l % 81] = coef[l];
    if (o < BS) sci[o] = cin_att[o * CIN + i];
    __syncthreads();

    float wb[9];
    const float* wp = w_base + ((size_t)o * CIN + i) * 9;
    #pragma unroll
    for (int s = 0; s < 9; ++s) wb[s] = wp[s];

    for (int b = 0; b < BS; ++b) {
        const float scale = sci[b] * out_att[b * COUT + o];
        float* outp = wsyn + (((size_t)b * CIN + i) * 9) * COUT + o;
        #pragma unroll
        for (int d = 0; d < 9; ++d) {
            float a = 0.f;
            #pragma unroll
            for (int s = 0; s < 9; ++s) a += sc[b][d * 9 + s] * wb[s];
            outp[(size_t)d * COUT] = a * scale;
        }
    }
}

__global__ __launch_bounds__(256, 3)
void conv_kernel(const float* __restrict__ x,
                 const float* __restrict__ wsyn,
                 const float* __restrict__ agg_b,
                 float* __restrict__ y) {
    const int tile = blockIdx.x;
    const int tx = tile % 5;
    const int ty = tile / 5;
    const int oBase = blockIdx.y * 64;
    const int b = blockIdx.z;

    __shared__ float xs[4][10][18];
    __shared__ float wsh[4][9][64];

    const int t  = threadIdx.x;
    const int og = t & 15;
    const int oL = og * 4;
    const int pg = t >> 4;
    const int r  = pg >> 1;
    const int c0 = (pg & 1) * 8;

    float acc[4][8];
    #pragma unroll
    for (int a = 0; a < 4; ++a)
        #pragma unroll
        for (int p = 0; p < 8; ++p) acc[a][p] = 0.f;

    const int row0 = ty * 8 - 1;
    const int col0 = tx * 16 - 1;
    const float* xb  = x + (size_t)b * CIN * NPIX;
    const float* wsb = wsyn + (size_t)b * CIN * 9 * COUT + oBase;

    for (int icb = 0; icb < CIN / 4; ++icb) {
        #pragma unroll
        for (int q = 0; q < 3; ++q) {
            const int l = t + q * 256;
            if (l < 720) {
                const int ic  = l / 180;
                const int rem = l % 180;
                const int rr  = rem / 18;
                const int cc  = rem % 18;
                const int gr = row0 + rr, gc = col0 + cc;
                float v = 0.f;
                if ((unsigned)gr < 80u && (unsigned)gc < 80u)
                    v = xb[(size_t)(icb * 4 + ic) * NPIX + gr * 80 + gc];
                ((float*)xs)[l] = v;
            }
        }
        #pragma unroll
        for (int q = 0; q < 9; ++q) {
            const int l = t + q * 256;
            const int ic  = l / 576;
            const int rem = l % 576;
            const int tap = rem / 64;
            const int o   = rem & 63;
            ((float*)wsh)[l] = wsb[(size_t)(icb * 4 + ic) * 9 * COUT + tap * COUT + o];
        }
        __syncthreads();

        #pragma unroll
        for (int ic = 0; ic < 4; ++ic) {
            float xr[3][10];
            #pragma unroll
            for (int dh = 0; dh < 3; ++dh)
                #pragma unroll
                for (int c = 0; c < 10; ++c) xr[dh][c] = xs[ic][r + dh][c0 + c];
            #pragma unroll
            for (int tap = 0; tap < 9; ++tap) {
                const int dh = tap / 3, dw = tap % 3;
                const float4 wv = *(const float4*)&wsh[ic][tap][oL];
                #pragma unroll
                for (int oo = 0; oo < 4; ++oo) {
                    const float wq = (&wv.x)[oo];
                    #pragma unroll
                    for (int p = 0; p < 8; ++p)
                        acc[oo][p] = fmaf(wq, xr[dh][p + dw], acc[oo][p]);
                }
            }
        }
        __syncthreads();
    }

    #pragma unroll
    for (int oo = 0; oo < 4; ++oo) {
        const int o = oBase + oL + oo;
        const float bv = agg_b[b * COUT + o];
        float* yp = y + (size_t)(b * COUT + o) * NPIX + (ty * 8 + r) * 80 + tx * 16 + c0;
        float4 v0 = make_float4(acc[oo][0] + bv, acc[oo][1] + bv,
                                acc[oo][2] + bv, acc[oo][3] + bv);
        float4 v1 = make_float4(acc[oo][4] + bv, acc[oo][5] + bv,
                                acc[oo][6] + bv, acc[oo][7] + bv);
        *(float4*)yp = v0;
        *((float4*)yp + 1) = v1;
    }
}

// ---------------------------------------------------------------------------
extern "C" void kernel_launch(void* const* d_in, const int* in_sizes, int n_in,
                              void* d_out, int out_size, void* d_ws, size_t ws_size,
                              hipStream_t stream) {
    const float* x       = (const float*)d_in[0];
    const float* w_base  = (const float*)d_in[1];
    const float* b_base  = (const float*)d_in[2];
    const float* b_extra = (const float*)d_in[3];
    const float* w_net   = (const float*)d_in[4];
    const float* w_nfc   = (const float*)d_in[5];
    const float* w_cin   = (const float*)d_in[6];
    const float* w_k2    = (const float*)d_in[7];
    const float* w_out   = (const float*)d_in[8];
    float* y = (float*)d_out;

    float* ws      = (float*)d_ws;
    float* pooled  = ws;
    float* cin_att = ws + 4096;
    float* out_att = ws + 8192;
    float* agg_b   = ws + 12288;
    float* coef    = ws + 16384;

    const size_t XT_OFF = 131072;                       // bytes
    const size_t WH_OFF = XT_OFF + (size_t)BS * NPIX * CIN * 2;   // + 52.4 MB
    const size_t NEED   = WH_OFF + (size_t)BS * 8 * 36 * 2048 * 2; // + 18.9 MB

    if (ws_size >= NEED) {
        _Float16* xt  = (_Float16*)((char*)d_ws + XT_OFF);
        _Float16* wh  = (_Float16*)((char*)d_ws + WH_OFF);
        pool_kernel<<<BS * CIN, 256, 0, stream>>>(x, pooled);
        xpose_kernel<<<dim3(100, BS), 256, 0, stream>>>(x, xt);
        attn_kernel<<<BS, 256, 0, stream>>>(pooled, b_base, b_extra, w_net, w_nfc,
                                            w_cin, w_k2, w_out,
                                            cin_att, out_att, agg_b, coef);
        wsyn_f16_kernel<<<dim3(8, 4, BS), 256, 0, stream>>>(w_base, cin_att,
                                                            out_att, coef, wh);
        conv_mfma_kernel<<<dim3(25, 4, BS), 256, 0, stream>>>(xt, wh, agg_b, y);
    } else {
        float* wsyn = ws + 17680;
        pool_kernel<<<BS * CIN, 256, 0, stream>>>(x, pooled);
        attn_kernel<<<BS, 256, 0, stream>>>(pooled, b_base, b_extra, w_net, w_nfc,
                                            w_cin, w_k2, w_out,
                                            cin_att, out_att, agg_b, coef);
        wsyn_kernel<<<CIN, 256, 0, stream>>>(w_base, cin_att, out_att, coef, wsyn);
        conv_kernel<<<dim3(50, 4, BS), 256, 0, stream>>>(x, wsyn, agg_b, y);
    }
}

// Round 7
// 374.258 us; speedup vs baseline: 1.5825x; 1.5825x over previous
//
#include <hip/hip_runtime.h>
#include <hip/hip_bf16.h>
#include <cstdint>
#include <cstddef>

// Problem constants
#define BS   16
#define CIN  256
#define COUT 256
#define HID  16
#define KNUM 5
#define TEMP 30.0f
#define NPIX 6400   // 80*80

typedef _Float16 half8 __attribute__((ext_vector_type(8)));
typedef _Float16 half4 __attribute__((ext_vector_type(4)));
typedef float    f32x4 __attribute__((ext_vector_type(4)));

// direct global->LDS async copy, 16B per lane. LDS dest must be wave-uniform
// (HW adds lane*16); global addr is per-lane.
__device__ __forceinline__ void gload_lds16(const void* g, void* l) {
    __builtin_amdgcn_global_load_lds(
        (const __attribute__((address_space(1))) unsigned int*)g,
        (__attribute__((address_space(3))) unsigned int*)l, 16, 0, 0);
}

// ---------------------------------------------------------------------------
// Kernel 1: global average pool (f32 x, exact).  x[b][c][6400] -> pooled[b*256+c]
// ---------------------------------------------------------------------------
__global__ void pool_kernel(const float* __restrict__ x, float* __restrict__ pooled) {
    const int bc = blockIdx.x;
    const float* p = x + (size_t)bc * NPIX;
    float s = 0.f;
    for (int i = threadIdx.x; i < NPIX; i += 256) s += p[i];
    #pragma unroll
    for (int off = 32; off; off >>= 1) s += __shfl_down(s, off, 64);
    __shared__ float red[4];
    if ((threadIdx.x & 63) == 0) red[threadIdx.x >> 6] = s;
    __syncthreads();
    if (threadIdx.x == 0)
        pooled[bc] = (red[0] + red[1] + red[2] + red[3]) * (1.f / (float)NPIX);
}

// ---------------------------------------------------------------------------
// Kernel 2: x transpose f32 -> f16 via LDS tile (v3).
// Block = 64 px x 256 c of one sample.
// Phase A: float4/lane loads (1 KB contiguous per wave-instr) -> LDS [c][64+4pad].
// Phase B: 8x b16 LDS gather per half8 -> fully coalesced 16 B global stores.
// Loads: 64 KB/block in 256 x 1KB instrs; stores: 32 KB coalesced.
// ---------------------------------------------------------------------------
__global__ __launch_bounds__(256)
void xpose_kernel(const float* __restrict__ x, _Float16* __restrict__ xt) {
    const int b = blockIdx.y, p0 = blockIdx.x * 64;
    __shared__ _Float16 tile[256 * 68];   // row stride 68 halves (34 words, odd*2)

    const int t = threadIdx.x;
    const int l16 = t & 15, cq = t >> 4;

    // Phase A: c = it*16 + cq, px-chunk = l16*4
    #pragma unroll
    for (int it = 0; it < 16; ++it) {
        const int c = it * 16 + cq;
        const float4 v = *(const float4*)(x + ((size_t)(b * CIN + c)) * NPIX
                                            + p0 + l16 * 4);
        half4 h;
        h[0] = (_Float16)v.x; h[1] = (_Float16)v.y;
        h[2] = (_Float16)v.z; h[3] = (_Float16)v.w;
        *(half4*)(tile + c * 68 + l16 * 4) = h;
    }
    __syncthreads();

    // Phase B: thread -> (lpx = t>>2, ch = t&3); 8 chunks of 8 channels
    const int lpx = t >> 2, ch = t & 3;
    _Float16* tp = xt + ((size_t)b * NPIX + p0 + lpx) * CIN;
    #pragma unroll
    for (int j = 0; j < 8; ++j) {
        const int c0 = ch * 8 + j * 32;
        half8 h;
        #pragma unroll
        for (int i = 0; i < 8; ++i) h[i] = tile[(c0 + i) * 68 + lpx];
        *(half8*)(tp + c0) = h;
    }
}

// ---------------------------------------------------------------------------
// Kernel 3: attention head (per sample). pooled holds MEAN.
//   coef[b][d][s] = k2_att[d] * sum_k n_att[k]*[P_k[d]==s]
// ---------------------------------------------------------------------------
__global__ void attn_kernel(const float* __restrict__ pooled,
                            const float* __restrict__ b_base,
                            const float* __restrict__ b_extra,
                            const float* __restrict__ w_net,
                            const float* __restrict__ w_nfc,
                            const float* __restrict__ w_cin,
                            const float* __restrict__ w_k2,
                            const float* __restrict__ w_out,
                            float* __restrict__ cin_att,
                            float* __restrict__ out_att,
                            float* __restrict__ agg_b,
                            float* __restrict__ coef) {
    const int b = blockIdx.x;
    const int t = threadIdx.x;
    __shared__ float sp[CIN];
    __shared__ float sh[HID];
    __shared__ float sn[KNUM];
    __shared__ float sk2[9];

    sp[t] = pooled[b * CIN + t];
    __syncthreads();

    if (t < HID) {
        float a = 0.f;
        for (int c = 0; c < CIN; ++c) a += sp[c] * w_net[t * CIN + c];
        sh[t] = fmaxf(a, 0.f);
    }
    __syncthreads();

    if (t == 0) {
        float l[KNUM], m = -1e30f;
        for (int k = 0; k < KNUM; ++k) {
            float a = 0.f;
            for (int j = 0; j < HID; ++j) a += sh[j] * w_nfc[k * HID + j];
            l[k] = a / TEMP;
            m = fmaxf(m, l[k]);
        }
        float ssum = 0.f;
        for (int k = 0; k < KNUM; ++k) { l[k] = __expf(l[k] - m); ssum += l[k]; }
        for (int k = 0; k < KNUM; ++k) sn[k] = l[k] / ssum;
    }
    if (t < 9) {
        float a = 0.f;
        for (int j = 0; j < HID; ++j) a += sh[j] * w_k2[t * HID + j];
        sk2[t] = 1.f / (1.f + __expf(-a));
    }
    __syncthreads();

    {
        float a = 0.f, o = 0.f;
        for (int j = 0; j < HID; ++j) {
            a += sh[j] * w_cin[t * HID + j];
            o += sh[j] * w_out[t * HID + j];
        }
        cin_att[b * CIN + t] = 1.f / (1.f + __expf(-a));
        out_att[b * COUT + t] = 1.f / (1.f + __expf(-o));
        float bb = sn[0] * b_base[t];
        for (int k = 1; k < KNUM; ++k) bb += sn[k] * b_extra[(k - 1) * COUT + t];
        agg_b[b * COUT + t] = bb;
    }

    if (t < 81) {
        const int P45[9]  = {3, 0, 1, 6, 4, 2, 7, 8, 5};
        const int P90[9]  = {6, 3, 0, 7, 4, 1, 8, 5, 2};
        const int P135[9] = {7, 6, 3, 8, 4, 0, 5, 2, 1};
        const int P180[9] = {8, 7, 6, 5, 4, 3, 2, 1, 0};
        const int d = t / 9, s = t % 9;
        float c = 0.f;
        if (d == s)        c += sn[0];
        if (P45[d]  == s)  c += sn[1];
        if (P90[d]  == s)  c += sn[2];
        if (P135[d] == s)  c += sn[3];
        if (P180[d] == s)  c += sn[4];
        coef[b * 81 + t] = c * sk2[d];
    }
}

// ---------------------------------------------------------------------------
// Kernel 4: weight synthesis, f16, MFMA A-fragment order:
//   wsyn[b][icb(8)][tap(9)][kb(4)][o(256)][j(8)]
//   value = out_att[b][o]*cin_att[b][i]*sum_s coef[b][tap][s]*w_base[o][i][s]
//   with i = icb*32 + kb*8 + j.
// ---------------------------------------------------------------------------
__global__ __launch_bounds__(256)
void wsyn_f16_kernel(const float* __restrict__ w_base,
                     const float* __restrict__ cin_att,
                     const float* __restrict__ out_att,
                     const float* __restrict__ coef,
                     _Float16* __restrict__ wsyn) {
    const int icb = blockIdx.x, og = blockIdx.y, b = blockIdx.z;
    const int t = threadIdx.x;
    const int kb = t >> 6, o_l = t & 63;
    const int o = og * 64 + o_l;
    const int i0 = icb * 32 + kb * 8;

    __shared__ float sc[81];
    if (t < 81) sc[t] = coef[b * 81 + t];
    __syncthreads();

    const float so = out_att[b * COUT + o];
    float wb[8][9], sci[8];
    const float* wp = w_base + ((size_t)o * CIN + i0) * 9;
    #pragma unroll
    for (int j = 0; j < 8; ++j) {
        sci[j] = cin_att[b * CIN + i0 + j] * so;
        #pragma unroll
        for (int s = 0; s < 9; ++s) wb[j][s] = wp[j * 9 + s];
    }
    #pragma unroll
    for (int tap = 0; tap < 9; ++tap) {
        half8 h;
        #pragma unroll
        for (int j = 0; j < 8; ++j) {
            float a = 0.f;
            #pragma unroll
            for (int s = 0; s < 9; ++s) a = fmaf(sc[tap * 9 + s], wb[j][s], a);
            h[j] = (_Float16)(a * sci[j]);
        }
        *(half8*)(wsyn + ((size_t)(b * 8 + icb) * 36 + tap * 4 + kb) * 2048
                        + (size_t)o * 8) = h;
    }
}

// ---------------------------------------------------------------------------
// Kernel 5: MFMA implicit-GEMM conv (round-4 structure + B-tile regroup).
// Block: 64 o x 256 px (16x16 spatial), one sample; 4 waves (wave = 4 px rows).
// W staged via global_load_lds (36 KB, A-frag linear order).
// x halo in LDS regrouped [row18][cgrp4][col18][8c] so staging writes and Bv
// ds_read_b128 are both canonical distinct-word patterns (conflict-free).
// LDS total 56.25 KB -> 2 blocks/CU.
// ---------------------------------------------------------------------------
__global__ __launch_bounds__(256, 2)
void conv_mfma_kernel(const _Float16* __restrict__ xt,
                      const _Float16* __restrict__ wsyn,
                      const float* __restrict__ agg_b,
                      float* __restrict__ y) {
    const int tile = blockIdx.x;          // 0..24
    const int tc = tile % 5, tr = tile / 5;
    const int og = blockIdx.y;
    const int b = blockIdx.z;

    __shared__ _Float16 wlds[18432];      // [(tap*4+kb)][64 o][8]  = 36 KB
    __shared__ _Float16 xlds[10368];      // [row18][grp4][col18][8c] = 20.25 KB

    const int t = threadIdx.x;
    const int w = t >> 6, lane = t & 63, l15 = lane & 15, l4 = lane >> 4;
    const int row0 = tr * 16 - 1, col0 = tc * 16 - 1;

    f32x4 acc[4][4];
    const f32x4 z = {0.f, 0.f, 0.f, 0.f};
    #pragma unroll
    for (int a = 0; a < 4; ++a)
        #pragma unroll
        for (int p = 0; p < 4; ++p) acc[a][p] = z;

    for (int icb = 0; icb < 8; ++icb) {
        // --- stage W: 36 KB linear copy via global_load_lds x16B ------------
        const _Float16* gw = wsyn + (size_t)(b * 8 + icb) * 73728 + og * 512;
        #pragma unroll
        for (int q = 0; q < 9; ++q) {
            const int L = q * 2048 + t * 8;        // half index in wlds
            const int tapkb = L >> 9;
            gload_lds16(gw + (size_t)tapkb * 2048 + (L & 511),
                        wlds + q * 2048 + w * 512);
        }
        // --- stage x halo: 18x18 px x 32 c, regrouped [row][grp][col][8c] ---
        const _Float16* gx = xt + (size_t)b * NPIX * CIN + icb * 32;
        #pragma unroll
        for (int it = 0; it < 6; ++it) {
            const int idx = t + it * 256;
            if (idx < 1296) {
                const int rc = idx >> 2, part = idx & 3;   // part = c-group
                const int rr = rc / 18, cc = rc % 18;
                const int gr = row0 + rr, gc = col0 + cc;
                uint4 v = make_uint4(0u, 0u, 0u, 0u);
                if ((unsigned)gr < 80u && (unsigned)gc < 80u)
                    v = *(const uint4*)(gx + (size_t)(gr * 80 + gc) * CIN + part * 8);
                *(uint4*)((char*)xlds + rr * 1152 + part * 288 + cc * 16) = v;
            }
        }
        __syncthreads();

        // --- compute: per tap, A frags (4 o-tiles) x B frags (4 px rows) ----
        #pragma unroll
        for (int tap = 0; tap < 9; ++tap) {
            const int dh = tap / 3, dw = tap % 3;
            half8 A[4], Bv[4];
            #pragma unroll
            for (int ot = 0; ot < 4; ++ot)
                A[ot] = *(const half8*)(wlds +
                        ((size_t)(tap * 4 + l4) * 64 + ot * 16 + l15) * 8);
            #pragma unroll
            for (int pt = 0; pt < 4; ++pt)
                Bv[pt] = *(const half8*)((const char*)xlds +
                        (((w * 4 + pt + dh) * 4 + l4) * 18 + l15 + dw) * 16);
            #pragma unroll
            for (int ot = 0; ot < 4; ++ot)
                #pragma unroll
                for (int pt = 0; pt < 4; ++pt)
                    acc[ot][pt] = __builtin_amdgcn_mfma_f32_16x16x32_f16(
                        A[ot], Bv[pt], acc[ot][pt], 0, 0, 0);
        }
        __syncthreads();
    }

    // --- epilogue: bias + store (coalesced per 16-lane group) ---------------
    const int prow0 = tr * 16 + w * 4;
    #pragma unroll
    for (int ot = 0; ot < 4; ++ot) {
        const int o = og * 64 + ot * 16 + l4 * 4;
        #pragma unroll
        for (int q = 0; q < 4; ++q) {
            const float bv = agg_b[b * COUT + o + q];
            #pragma unroll
            for (int pt = 0; pt < 4; ++pt)
                y[(size_t)(b * COUT + o + q) * NPIX + (prow0 + pt) * 80
                  + tc * 16 + l15] = acc[ot][pt][q] + bv;
        }
    }
}

// ===========================================================================
// Fallback fp32 path (proven correct at 1683 us) — used only if ws too small.
// ===========================================================================
__global__ void wsyn_kernel(const float* __restrict__ w_base,
                            const float* __restrict__ cin_att,
                            const float* __restrict__ out_att,
                            const float* __restrict__ coef,
                            float* __restrict__ wsyn) {
    const int i = blockIdx.x;
    const int o = threadIdx.x;
    __shared__ float sc[BS][81];
    __shared__ float sci[BS];
    for (int l = o; l < BS * 81; l += 256) sc[l / 81][l % 81] = coef[l];
    if (o < BS) sci[o] = cin_att[o * CIN + i];
    __syncthreads();

    float wb[9];
    const float* wp = w_base + ((size_t)o * CIN + i) * 9;
    #pragma unroll
    for (int s = 0; s < 9; ++s) wb[s] = wp[s];

    for (int b = 0; b < BS; ++b) {
        const float scale = sci[b] * out_att[b * COUT + o];
        float* outp = wsyn + (((size_t)b * CIN + i) * 9) * COUT + o;
        #pragma unroll
        for (int d = 0; d < 9; ++d) {
            float a = 0.f;
            #pragma unroll
            for (int s = 0; s < 9; ++s) a += sc[b][d * 9 + s] * wb[s];
            outp[(size_t)d * COUT] = a * scale;
        }
    }
}

__global__ __launch_bounds__(256, 3)
void conv_kernel(const float* __restrict__ x,
                 const float* __restrict__ wsyn,
                 const float* __restrict__ agg_b,
                 float* __restrict__ y) {
    const int tile = blockIdx.x;
    const int tx = tile % 5;
    const int ty = tile / 5;
    const int oBase = blockIdx.y * 64;
    const int b = blockIdx.z;

    __shared__ float xs[4][10][18];
    __shared__ float wsh[4][9][64];

    const int t  = threadIdx.x;
    const int og = t & 15;
    const int oL = og * 4;
    const int pg = t >> 4;
    const int r  = pg >> 1;
    const int c0 = (pg & 1) * 8;

    float acc[4][8];
    #pragma unroll
    for (int a = 0; a < 4; ++a)
        #pragma unroll
        for (int p = 0; p < 8; ++p) acc[a][p] = 0.f;

    const int row0 = ty * 8 - 1;
    const int col0 = tx * 16 - 1;
    const float* xb  = x + (size_t)b * CIN * NPIX;
    const float* wsb = wsyn + (size_t)b * CIN * 9 * COUT + oBase;

    for (int icb = 0; icb < CIN / 4; ++icb) {
        #pragma unroll
        for (int q = 0; q < 3; ++q) {
            const int l = t + q * 256;
            if (l < 720) {
                const int ic  = l / 180;
                const int rem = l % 180;
                const int rr  = rem / 18;
                const int cc  = rem % 18;
                const int gr = row0 + rr, gc = col0 + cc;
                float v = 0.f;
                if ((unsigned)gr < 80u && (unsigned)gc < 80u)
                    v = xb[(size_t)(icb * 4 + ic) * NPIX + gr * 80 + gc];
                ((float*)xs)[l] = v;
            }
        }
        #pragma unroll
        for (int q = 0; q < 9; ++q) {
            const int l = t + q * 256;
            const int ic  = l / 576;
            const int rem = l % 576;
            const int tap = rem / 64;
            const int o   = rem & 63;
            ((float*)wsh)[l] = wsb[(size_t)(icb * 4 + ic) * 9 * COUT + tap * COUT + o];
        }
        __syncthreads();

        #pragma unroll
        for (int ic = 0; ic < 4; ++ic) {
            float xr[3][10];
            #pragma unroll
            for (int dh = 0; dh < 3; ++dh)
                #pragma unroll
                for (int c = 0; c < 10; ++c) xr[dh][c] = xs[ic][r + dh][c0 + c];
            #pragma unroll
            for (int tap = 0; tap < 9; ++tap) {
                const int dh = tap / 3, dw = tap % 3;
                const float4 wv = *(const float4*)&wsh[ic][tap][oL];
                #pragma unroll
                for (int oo = 0; oo < 4; ++oo) {
                    const float wq = (&wv.x)[oo];
                    #pragma unroll
                    for (int p = 0; p < 8; ++p)
                        acc[oo][p] = fmaf(wq, xr[dh][p + dw], acc[oo][p]);
                }
            }
        }
        __syncthreads();
    }

    #pragma unroll
    for (int oo = 0; oo < 4; ++oo) {
        const int o = oBase + oL + oo;
        const float bv = agg_b[b * COUT + o];
        float* yp = y + (size_t)(b * COUT + o) * NPIX + (ty * 8 + r) * 80 + tx * 16 + c0;
        float4 v0 = make_float4(acc[oo][0] + bv, acc[oo][1] + bv,
                                acc[oo][2] + bv, acc[oo][3] + bv);
        float4 v1 = make_float4(acc[oo][4] + bv, acc[oo][5] + bv,
                                acc[oo][6] + bv, acc[oo][7] + bv);
        *(float4*)yp = v0;
        *((float4*)yp + 1) = v1;
    }
}

// ---------------------------------------------------------------------------
extern "C" void kernel_launch(void* const* d_in, const int* in_sizes, int n_in,
                              void* d_out, int out_size, void* d_ws, size_t ws_size,
                              hipStream_t stream) {
    const float* x       = (const float*)d_in[0];
    const float* w_base  = (const float*)d_in[1];
    const float* b_base  = (const float*)d_in[2];
    const float* b_extra = (const float*)d_in[3];
    const float* w_net   = (const float*)d_in[4];
    const float* w_nfc   = (const float*)d_in[5];
    const float* w_cin   = (const float*)d_in[6];
    const float* w_k2    = (const float*)d_in[7];
    const float* w_out   = (const float*)d_in[8];
    float* y = (float*)d_out;

    float* ws      = (float*)d_ws;
    float* pooled  = ws;
    float* cin_att = ws + 4096;
    float* out_att = ws + 8192;
    float* agg_b   = ws + 12288;
    float* coef    = ws + 16384;

    const size_t XT_OFF = 131072;                       // bytes
    const size_t WH_OFF = XT_OFF + (size_t)BS * NPIX * CIN * 2;   // + 52.4 MB
    const size_t NEED   = WH_OFF + (size_t)BS * 8 * 36 * 2048 * 2; // + 18.9 MB

    if (ws_size >= NEED) {
        _Float16* xt  = (_Float16*)((char*)d_ws + XT_OFF);
        _Float16* wh  = (_Float16*)((char*)d_ws + WH_OFF);
        pool_kernel<<<BS * CIN, 256, 0, stream>>>(x, pooled);
        xpose_kernel<<<dim3(100, BS), 256, 0, stream>>>(x, xt);
        attn_kernel<<<BS, 256, 0, stream>>>(pooled, b_base, b_extra, w_net, w_nfc,
                                            w_cin, w_k2, w_out,
                                            cin_att, out_att, agg_b, coef);
        wsyn_f16_kernel<<<dim3(8, 4, BS), 256, 0, stream>>>(w_base, cin_att,
                                                            out_att, coef, wh);
        conv_mfma_kernel<<<dim3(25, 4, BS), 256, 0, stream>>>(xt, wh, agg_b, y);
    } else {
        float* wsyn = ws + 17680;
        pool_kernel<<<BS * CIN, 256, 0, stream>>>(x, pooled);
        attn_kernel<<<BS, 256, 0, stream>>>(pooled, b_base, b_extra, w_net, w_nfc,
                                            w_cin, w_k2, w_out,
                                            cin_att, out_att, agg_b, coef);
        wsyn_kernel<<<CIN, 256, 0, stream>>>(w_base, cin_att, out_att, coef, wsyn);
        conv_kernel<<<dim3(50, 4, BS), 256, 0, stream>>>(x, wsyn, agg_b, y);
    }
}

// Round 8
// 354.926 us; speedup vs baseline: 1.6687x; 1.0545x over previous
//
#include <hip/hip_runtime.h>
#include <hip/hip_bf16.h>
#include <cstdint>
#include <cstddef>

// Problem constants
#define BS   16
#define CIN  256
#define COUT 256
#define HID  16
#define KNUM 5
#define TEMP 30.0f
#define NPIX 6400   // 80*80

typedef _Float16 half8 __attribute__((ext_vector_type(8)));
typedef _Float16 half4 __attribute__((ext_vector_type(4)));
typedef float    f32x4 __attribute__((ext_vector_type(4)));

// direct global->LDS async copy, 16B per lane. LDS dest must be wave-uniform
// (HW adds lane*16); global addr is per-lane.
__device__ __forceinline__ void gload_lds16(const void* g, void* l) {
    __builtin_amdgcn_global_load_lds(
        (const __attribute__((address_space(1))) unsigned int*)g,
        (__attribute__((address_space(3))) unsigned int*)l, 16, 0, 0);
}

// ---------------------------------------------------------------------------
// zero pooled accumulator (ws is poisoned 0xAA before every timed launch)
// ---------------------------------------------------------------------------
__global__ void zero_pool_kernel(float* __restrict__ pooled) {
    pooled[blockIdx.x * 256 + threadIdx.x] = 0.f;
}

// ---------------------------------------------------------------------------
// Kernel 2: x transpose f32 -> f16, channel-blocked layout + fused pool.
//   x[b][c][px] -> xt[b][icb][px][32c]   (icb = c/32)
// grid (25, 8, 16) = (px-block of 256, icb, b); 256 threads.
// Phase A: thread (ch = t>>3, fq = t&7): 8 float4 loads (128 B contiguous per
//          ch per wave) -> LDS tile[32ch][258] via b64 writes; per-ch partial
//          sum -> 8-lane shuffle reduce -> one atomicAdd per ch.
// Phase B: thread px = t: 32 b16 gathers (word = ch*129 + px>>1: consecutive
//          banks, pair-broadcast, conflict-free) -> 64 B contiguous store.
// Block: 32 KB read (1 KB segments), 16 KB write (fully contiguous).
// ---------------------------------------------------------------------------
__global__ __launch_bounds__(256)
void xpose_kernel(const float* __restrict__ x, _Float16* __restrict__ xt,
                  float* __restrict__ pooled) {
    const int p0 = blockIdx.x * 256, icb = blockIdx.y, b = blockIdx.z;
    __shared__ _Float16 tile[32 * 258];

    const int t = threadIdx.x;
    const int ch = t >> 3, fq = t & 7;
    const float* xp = x + ((size_t)(b * CIN + icb * 32 + ch)) * NPIX + p0;

    float s = 0.f;
    #pragma unroll
    for (int it = 0; it < 8; ++it) {
        const int px0 = (fq + it * 8) * 4;          // 0..252 step 4
        const float4 v = *(const float4*)(xp + px0);
        s += v.x + v.y + v.z + v.w;
        half4 h;
        h[0] = (_Float16)v.x; h[1] = (_Float16)v.y;
        h[2] = (_Float16)v.z; h[3] = (_Float16)v.w;
        *(half4*)(tile + ch * 258 + px0) = h;
    }
    // pool partial: lanes {ch*8 + 0..7} hold same ch
    s += __shfl_xor(s, 1, 64);
    s += __shfl_xor(s, 2, 64);
    s += __shfl_xor(s, 4, 64);
    if (fq == 0) atomicAdd(&pooled[b * CIN + icb * 32 + ch], s);
    __syncthreads();

    // Phase B: gather 32 channels for px = t, store 64 B contiguous
    const int px = t;
    _Float16 vals[32];
    #pragma unroll
    for (int c = 0; c < 32; ++c) vals[c] = tile[c * 258 + px];
    _Float16* tp = xt + ((size_t)(b * 8 + icb) * NPIX + p0 + px) * 32;
    #pragma unroll
    for (int q = 0; q < 4; ++q) {
        half8 h;
        #pragma unroll
        for (int j = 0; j < 8; ++j) h[j] = vals[q * 8 + j];
        *(half8*)(tp + q * 8) = h;
    }
}

// ---------------------------------------------------------------------------
// Kernel 3: attention head (per sample). pooled holds SUM (scale=1/NPIX) or
// MEAN (fallback, scale=1).  coef[b][d][s] = k2[d]*sum_k n[k]*[P_k[d]==s]
// ---------------------------------------------------------------------------
__global__ void attn_kernel(const float* __restrict__ pooled,
                            const float* __restrict__ b_base,
                            const float* __restrict__ b_extra,
                            const float* __restrict__ w_net,
                            const float* __restrict__ w_nfc,
                            const float* __restrict__ w_cin,
                            const float* __restrict__ w_k2,
                            const float* __restrict__ w_out,
                            float* __restrict__ cin_att,
                            float* __restrict__ out_att,
                            float* __restrict__ agg_b,
                            float* __restrict__ coef,
                            float pool_scale) {
    const int b = blockIdx.x;
    const int t = threadIdx.x;
    __shared__ float sp[CIN];
    __shared__ float sh[HID];
    __shared__ float sn[KNUM];
    __shared__ float sk2[9];

    sp[t] = pooled[b * CIN + t] * pool_scale;
    __syncthreads();

    if (t < HID) {
        float a = 0.f;
        for (int c = 0; c < CIN; ++c) a += sp[c] * w_net[t * CIN + c];
        sh[t] = fmaxf(a, 0.f);
    }
    __syncthreads();

    if (t == 0) {
        float l[KNUM], m = -1e30f;
        for (int k = 0; k < KNUM; ++k) {
            float a = 0.f;
            for (int j = 0; j < HID; ++j) a += sh[j] * w_nfc[k * HID + j];
            l[k] = a / TEMP;
            m = fmaxf(m, l[k]);
        }
        float ssum = 0.f;
        for (int k = 0; k < KNUM; ++k) { l[k] = __expf(l[k] - m); ssum += l[k]; }
        for (int k = 0; k < KNUM; ++k) sn[k] = l[k] / ssum;
    }
    if (t < 9) {
        float a = 0.f;
        for (int j = 0; j < HID; ++j) a += sh[j] * w_k2[t * HID + j];
        sk2[t] = 1.f / (1.f + __expf(-a));
    }
    __syncthreads();

    {
        float a = 0.f, o = 0.f;
        for (int j = 0; j < HID; ++j) {
            a += sh[j] * w_cin[t * HID + j];
            o += sh[j] * w_out[t * HID + j];
        }
        cin_att[b * CIN + t] = 1.f / (1.f + __expf(-a));
        out_att[b * COUT + t] = 1.f / (1.f + __expf(-o));
        float bb = sn[0] * b_base[t];
        for (int k = 1; k < KNUM; ++k) bb += sn[k] * b_extra[(k - 1) * COUT + t];
        agg_b[b * COUT + t] = bb;
    }

    if (t < 81) {
        const int P45[9]  = {3, 0, 1, 6, 4, 2, 7, 8, 5};
        const int P90[9]  = {6, 3, 0, 7, 4, 1, 8, 5, 2};
        const int P135[9] = {7, 6, 3, 8, 4, 0, 5, 2, 1};
        const int P180[9] = {8, 7, 6, 5, 4, 3, 2, 1, 0};
        const int d = t / 9, s = t % 9;
        float c = 0.f;
        if (d == s)        c += sn[0];
        if (P45[d]  == s)  c += sn[1];
        if (P90[d]  == s)  c += sn[2];
        if (P135[d] == s)  c += sn[3];
        if (P180[d] == s)  c += sn[4];
        coef[b * 81 + t] = c * sk2[d];
    }
}

// ---------------------------------------------------------------------------
// Kernel 4: weight synthesis, f16, MFMA A-fragment order:
//   wsyn[b][icb(8)][tap(9)][kb(4)][o(256)][j(8)]
//   value = out_att[b][o]*cin_att[b][i]*sum_s coef[b][tap][s]*w_base[o][i][s]
//   with i = icb*32 + kb*8 + j.
// ---------------------------------------------------------------------------
__global__ __launch_bounds__(256)
void wsyn_f16_kernel(const float* __restrict__ w_base,
                     const float* __restrict__ cin_att,
                     const float* __restrict__ out_att,
                     const float* __restrict__ coef,
                     _Float16* __restrict__ wsyn) {
    const int icb = blockIdx.x, og = blockIdx.y, b = blockIdx.z;
    const int t = threadIdx.x;
    const int kb = t >> 6, o_l = t & 63;
    const int o = og * 64 + o_l;
    const int i0 = icb * 32 + kb * 8;

    __shared__ float sc[81];
    if (t < 81) sc[t] = coef[b * 81 + t];
    __syncthreads();

    const float so = out_att[b * COUT + o];
    float wb[8][9], sci[8];
    const float* wp = w_base + ((size_t)o * CIN + i0) * 9;
    #pragma unroll
    for (int j = 0; j < 8; ++j) {
        sci[j] = cin_att[b * CIN + i0 + j] * so;
        #pragma unroll
        for (int s = 0; s < 9; ++s) wb[j][s] = wp[j * 9 + s];
    }
    #pragma unroll
    for (int tap = 0; tap < 9; ++tap) {
        half8 h;
        #pragma unroll
        for (int j = 0; j < 8; ++j) {
            float a = 0.f;
            #pragma unroll
            for (int s = 0; s < 9; ++s) a = fmaf(sc[tap * 9 + s], wb[j][s], a);
            h[j] = (_Float16)(a * sci[j]);
        }
        *(half8*)(wsyn + ((size_t)(b * 8 + icb) * 36 + tap * 4 + kb) * 2048
                        + (size_t)o * 8) = h;
    }
}

// ---------------------------------------------------------------------------
// Kernel 5: MFMA implicit-GEMM conv (proven 148 us structure; only the xt
// address formula changed for the new [b][icb][px][32c] layout — per halo
// pixel the 4 part-lanes now read 64 B contiguous).
// ---------------------------------------------------------------------------
__global__ __launch_bounds__(256, 2)
void conv_mfma_kernel(const _Float16* __restrict__ xt,
                      const _Float16* __restrict__ wsyn,
                      const float* __restrict__ agg_b,
                      float* __restrict__ y) {
    const int tile = blockIdx.x;          // 0..24
    const int tc = tile % 5, tr = tile / 5;
    const int og = blockIdx.y;
    const int b = blockIdx.z;

    __shared__ _Float16 wlds[18432];      // [(tap*4+kb)][64 o][8]  = 36 KB
    __shared__ _Float16 xlds[10368];      // [row18][grp4][col18][8c] = 20.25 KB

    const int t = threadIdx.x;
    const int w = t >> 6, lane = t & 63, l15 = lane & 15, l4 = lane >> 4;
    const int row0 = tr * 16 - 1, col0 = tc * 16 - 1;

    f32x4 acc[4][4];
    const f32x4 z = {0.f, 0.f, 0.f, 0.f};
    #pragma unroll
    for (int a = 0; a < 4; ++a)
        #pragma unroll
        for (int p = 0; p < 4; ++p) acc[a][p] = z;

    for (int icb = 0; icb < 8; ++icb) {
        // --- stage W: 36 KB linear copy via global_load_lds x16B ------------
        const _Float16* gw = wsyn + (size_t)(b * 8 + icb) * 73728 + og * 512;
        #pragma unroll
        for (int q = 0; q < 9; ++q) {
            const int L = q * 2048 + t * 8;        // half index in wlds
            const int tapkb = L >> 9;
            gload_lds16(gw + (size_t)tapkb * 2048 + (L & 511),
                        wlds + q * 2048 + w * 512);
        }
        // --- stage x halo: 18x18 px x 32 c; 64 B contiguous per px ----------
        const _Float16* gx = xt + (size_t)(b * 8 + icb) * NPIX * 32;
        #pragma unroll
        for (int it = 0; it < 6; ++it) {
            const int idx = t + it * 256;
            if (idx < 1296) {
                const int rc = idx >> 2, part = idx & 3;   // part = c-group
                const int rr = rc / 18, cc = rc % 18;
                const int gr = row0 + rr, gc = col0 + cc;
                uint4 v = make_uint4(0u, 0u, 0u, 0u);
                if ((unsigned)gr < 80u && (unsigned)gc < 80u)
                    v = *(const uint4*)(gx + (size_t)(gr * 80 + gc) * 32 + part * 8);
                *(uint4*)((char*)xlds + rr * 1152 + part * 288 + cc * 16) = v;
            }
        }
        __syncthreads();

        // --- compute: per tap, A frags (4 o-tiles) x B frags (4 px rows) ----
        #pragma unroll
        for (int tap = 0; tap < 9; ++tap) {
            const int dh = tap / 3, dw = tap % 3;
            half8 A[4], Bv[4];
            #pragma unroll
            for (int ot = 0; ot < 4; ++ot)
                A[ot] = *(const half8*)(wlds +
                        ((size_t)(tap * 4 + l4) * 64 + ot * 16 + l15) * 8);
            #pragma unroll
            for (int pt = 0; pt < 4; ++pt)
                Bv[pt] = *(const half8*)((const char*)xlds +
                        (((w * 4 + pt + dh) * 4 + l4) * 18 + l15 + dw) * 16);
            #pragma unroll
            for (int ot = 0; ot < 4; ++ot)
                #pragma unroll
                for (int pt = 0; pt < 4; ++pt)
                    acc[ot][pt] = __builtin_amdgcn_mfma_f32_16x16x32_f16(
                        A[ot], Bv[pt], acc[ot][pt], 0, 0, 0);
        }
        __syncthreads();
    }

    // --- epilogue: bias + store (coalesced per 16-lane group) ---------------
    const int prow0 = tr * 16 + w * 4;
    #pragma unroll
    for (int ot = 0; ot < 4; ++ot) {
        const int o = og * 64 + ot * 16 + l4 * 4;
        #pragma unroll
        for (int q = 0; q < 4; ++q) {
            const float bv = agg_b[b * COUT + o + q];
            #pragma unroll
            for (int pt = 0; pt < 4; ++pt)
                y[(size_t)(b * COUT + o + q) * NPIX + (prow0 + pt) * 80
                  + tc * 16 + l15] = acc[ot][pt][q] + bv;
        }
    }
}

// ===========================================================================
// Fallback fp32 path (proven correct at 1683 us) — used only if ws too small.
// ===========================================================================
__global__ void pool_kernel(const float* __restrict__ x, float* __restrict__ pooled) {
    const int bc = blockIdx.x;
    const float* p = x + (size_t)bc * NPIX;
    float s = 0.f;
    for (int i = threadIdx.x; i < NPIX; i += 256) s += p[i];
    #pragma unroll
    for (int off = 32; off; off >>= 1) s += __shfl_down(s, off, 64);
    __shared__ float red[4];
    if ((threadIdx.x & 63) == 0) red[threadIdx.x >> 6] = s;
    __syncthreads();
    if (threadIdx.x == 0)
        pooled[bc] = (red[0] + red[1] + red[2] + red[3]) * (1.f / (float)NPIX);
}

__global__ void wsyn_kernel(const float* __restrict__ w_base,
                            const float* __restrict__ cin_att,
                            const float* __restrict__ out_att,
                            const float* __restrict__ coef,
                            float* __restrict__ wsyn) {
    const int i = blockIdx.x;
    const int o = threadIdx.x;
    __shared__ float sc[BS][81];
    __shared__ float sci[BS];
    for (int l = o; l < BS * 81; l += 256) sc[l / 81][l % 81] = coef[l];
    if (o < BS) sci[o] = cin_att[o * CIN + i];
    __syncthreads();

    float wb[9];
    const float* wp = w_base + ((size_t)o * CIN + i) * 9;
    #pragma unroll
    for (int s = 0; s < 9; ++s) wb[s] = wp[s];

    for (int b = 0; b < BS; ++b) {
        const float scale = sci[b] * out_att[b * COUT + o];
        float* outp = wsyn + (((size_t)b * CIN + i) * 9) * COUT + o;
        #pragma unroll
        for (int d = 0; d < 9; ++d) {
            float a = 0.f;
            #pragma unroll
            for (int s = 0; s < 9; ++s) a += sc[b][d * 9 + s] * wb[s];
            outp[(size_t)d * COUT] = a * scale;
        }
    }
}

__global__ __launch_bounds__(256, 3)
void conv_kernel(const float* __restrict__ x,
                 const float* __restrict__ wsyn,
                 const float* __restrict__ agg_b,
                 float* __restrict__ y) {
    const int tile = blockIdx.x;
    const int tx = tile % 5;
    const int ty = tile / 5;
    const int oBase = blockIdx.y * 64;
    const int b = blockIdx.z;

    __shared__ float xs[4][10][18];
    __shared__ float wsh[4][9][64];

    const int t  = threadIdx.x;
    const int og = t & 15;
    const int oL = og * 4;
    const int pg = t >> 4;
    const int r  = pg >> 1;
    const int c0 = (pg & 1) * 8;

    float acc[4][8];
    #pragma unroll
    for (int a = 0; a < 4; ++a)
        #pragma unroll
        for (int p = 0; p < 8; ++p) acc[a][p] = 0.f;

    const int row0 = ty * 8 - 1;
    const int col0 = tx * 16 - 1;
    const float* xb  = x + (size_t)b * CIN * NPIX;
    const float* wsb = wsyn + (size_t)b * CIN * 9 * COUT + oBase;

    for (int icb = 0; icb < CIN / 4; ++icb) {
        #pragma unroll
        for (int q = 0; q < 3; ++q) {
            const int l = t + q * 256;
            if (l < 720) {
                const int ic  = l / 180;
                const int rem = l % 180;
                const int rr  = rem / 18;
                const int cc  = rem % 18;
                const int gr = row0 + rr, gc = col0 + cc;
                float v = 0.f;
                if ((unsigned)gr < 80u && (unsigned)gc < 80u)
                    v = xb[(size_t)(icb * 4 + ic) * NPIX + gr * 80 + gc];
                ((float*)xs)[l] = v;
            }
        }
        #pragma unroll
        for (int q = 0; q < 9; ++q) {
            const int l = t + q * 256;
            const int ic  = l / 576;
            const int rem = l % 576;
            const int tap = rem / 64;
            const int o   = rem & 63;
            ((float*)wsh)[l] = wsb[(size_t)(icb * 4 + ic) * 9 * COUT + tap * COUT + o];
        }
        __syncthreads();

        #pragma unroll
        for (int ic = 0; ic < 4; ++ic) {
            float xr[3][10];
            #pragma unroll
            for (int dh = 0; dh < 3; ++dh)
                #pragma unroll
                for (int c = 0; c < 10; ++c) xr[dh][c] = xs[ic][r + dh][c0 + c];
            #pragma unroll
            for (int tap = 0; tap < 9; ++tap) {
                const int dh = tap / 3, dw = tap % 3;
                const float4 wv = *(const float4*)&wsh[ic][tap][oL];
                #pragma unroll
                for (int oo = 0; oo < 4; ++oo) {
                    const float wq = (&wv.x)[oo];
                    #pragma unroll
                    for (int p = 0; p < 8; ++p)
                        acc[oo][p] = fmaf(wq, xr[dh][p + dw], acc[oo][p]);
                }
            }
        }
        __syncthreads();
    }

    #pragma unroll
    for (int oo = 0; oo < 4; ++oo) {
        const int o = oBase + oL + oo;
        const float bv = agg_b[b * COUT + o];
        float* yp = y + (size_t)(b * COUT + o) * NPIX + (ty * 8 + r) * 80 + tx * 16 + c0;
        float4 v0 = make_float4(acc[oo][0] + bv, acc[oo][1] + bv,
                                acc[oo][2] + bv, acc[oo][3] + bv);
        float4 v1 = make_float4(acc[oo][4] + bv, acc[oo][5] + bv,
                                acc[oo][6] + bv, acc[oo][7] + bv);
        *(float4*)yp = v0;
        *((float4*)yp + 1) = v1;
    }
}

// ---------------------------------------------------------------------------
extern "C" void kernel_launch(void* const* d_in, const int* in_sizes, int n_in,
                              void* d_out, int out_size, void* d_ws, size_t ws_size,
                              hipStream_t stream) {
    const float* x       = (const float*)d_in[0];
    const float* w_base  = (const float*)d_in[1];
    const float* b_base  = (const float*)d_in[2];
    const float* b_extra = (const float*)d_in[3];
    const float* w_net   = (const float*)d_in[4];
    const float* w_nfc   = (const float*)d_in[5];
    const float* w_cin   = (const float*)d_in[6];
    const float* w_k2    = (const float*)d_in[7];
    const float* w_out   = (const float*)d_in[8];
    float* y = (float*)d_out;

    float* ws      = (float*)d_ws;
    float* pooled  = ws;
    float* cin_att = ws + 4096;
    float* out_att = ws + 8192;
    float* agg_b   = ws + 12288;
    float* coef    = ws + 16384;

    const size_t XT_OFF = 131072;                       // bytes
    const size_t WH_OFF = XT_OFF + (size_t)BS * NPIX * CIN * 2;   // + 52.4 MB
    const size_t NEED   = WH_OFF + (size_t)BS * 8 * 36 * 2048 * 2; // + 18.9 MB

    if (ws_size >= NEED) {
        _Float16* xt  = (_Float16*)((char*)d_ws + XT_OFF);
        _Float16* wh  = (_Float16*)((char*)d_ws + WH_OFF);
        zero_pool_kernel<<<BS, 256, 0, stream>>>(pooled);
        xpose_kernel<<<dim3(25, 8, BS), 256, 0, stream>>>(x, xt, pooled);
        attn_kernel<<<BS, 256, 0, stream>>>(pooled, b_base, b_extra, w_net, w_nfc,
                                            w_cin, w_k2, w_out,
                                            cin_att, out_att, agg_b, coef,
                                            1.f / (float)NPIX);
        wsyn_f16_kernel<<<dim3(8, 4, BS), 256, 0, stream>>>(w_base, cin_att,
                                                            out_att, coef, wh);
        conv_mfma_kernel<<<dim3(25, 4, BS), 256, 0, stream>>>(xt, wh, agg_b, y);
    } else {
        float* wsyn = ws + 17680;
        pool_kernel<<<BS * CIN, 256, 0, stream>>>(x, pooled);
        attn_kernel<<<BS, 256, 0, stream>>>(pooled, b_base, b_extra, w_net, w_nfc,
                                            w_cin, w_k2, w_out,
                                            cin_att, out_att, agg_b, coef, 1.f);
        wsyn_kernel<<<CIN, 256, 0, stream>>>(w_base, cin_att, out_att, coef, wsyn);
        conv_kernel<<<dim3(50, 4, BS), 256, 0, stream>>>(x, wsyn, agg_b, y);
    }
}